// Round 8
// baseline (401.211 us; speedup 1.0000x reference)
//
#include <hip/hip_runtime.h>

#define BB 8
#define LL 512
#define HH 8
#define BIGV (1e9f)

typedef unsigned short u16;
typedef __attribute__((ext_vector_type(8))) short bf16x8;
typedef __attribute__((ext_vector_type(4))) short s16x4;
typedef __attribute__((ext_vector_type(4))) float f32x4;

#define MFMA(a,b,c) __builtin_amdgcn_mfma_f32_16x16x32_bf16(a,b,c,0,0,0)

__device__ __forceinline__ u16 f2b(float f){
  unsigned u = __float_as_uint(f);
  u = (u + 0x7fffu + ((u>>16)&1u)) >> 16;
  return (u16)u;
}
__device__ __forceinline__ float b2f(u16 s){ return __uint_as_float(((unsigned)s)<<16); }
__device__ __forceinline__ bf16x8 ldb8(const u16* p){ return *(const bf16x8*)p; }

__device__ __forceinline__ float wred_max(float v){
  #pragma unroll
  for(int off=32;off>0;off>>=1) v = fmaxf(v, __shfl_xor(v, off, 64));
  return v;
}
__device__ __forceinline__ float wred_sum(float v){
  #pragma unroll
  for(int off=32;off>0;off>>=1) v += __shfl_xor(v, off, 64);
  return v;
}
__device__ __forceinline__ float g16_sum(float v){
  v += __shfl_xor(v,1,64); v += __shfl_xor(v,2,64);
  v += __shfl_xor(v,4,64); v += __shfl_xor(v,8,64);
  return v;
}

// ---- tables: T4t[c][b][a], Tt2[c][a][b], Gt[a][j], Gt2[j][a] ----
__global__ void kp_prep(const float* __restrict__ T, const float* __restrict__ gw,
                        u16* __restrict__ T4t, u16* __restrict__ Tt2,
                        u16* __restrict__ Gt, u16* __restrict__ Gt2){
  int idx = blockIdx.x*256 + threadIdx.x;   // < 32768
  { int c=idx>>12, b=(idx>>6)&63, a=idx&63; T4t[idx] = f2b(T[(a*64+b)*8+c]); }
  { int c=idx>>12, a=(idx>>6)&63, b=idx&63; Tt2[idx] = f2b(T[(a*64+b)*8+c]); }
  if(idx < 4096){
    int a=idx>>6, j=idx&63;
    Gt[idx]  = f2b(gw[j*64+a]);   // Gt[a][j]
    Gt2[idx] = f2b(gw[idx]);      // Gt2[j][a]
  }
}

// ---- k0: unary = (x+pe)*m1 ; qzstate = unary ; mf = mask as float ----
__global__ void k0_init(const float* __restrict__ x, const int* __restrict__ mask,
                        float* __restrict__ unary, float* __restrict__ qzstate,
                        float* __restrict__ mf){
  int idx = blockIdx.x*256 + threadIdx.x;
  int d = idx & 63; int row = idx >> 6;
  int pos = row & (LL-1);
  int k2 = d & ~1;
  float div = __expf(-(float)k2 * 0.14391156962f);  // ln(10000)/64
  float arg = (float)pos * div;
  float pe = (d & 1) ? cosf(arg) : sinf(arg);
  float mk = (mask[row] != 0) ? 1.f : 0.f;
  float u = (x[idx] + pe) * mk;
  unary[idx] = u; qzstate[idx] = u;
  if(d == 0) mf[row] = mk;
}

// ---- kA: softmax64 -> qzb ; P2 softmax + Mg = P2@gw -> MgF ----
__global__ __launch_bounds__(256) void kA(const float* __restrict__ qzstate,
      const int* __restrict__ mask, const u16* __restrict__ Gt2, const u16* __restrict__ Gt,
      u16* __restrict__ qzb, float* __restrict__ MgF){
  __shared__ u16 qlds[64*72];
  __shared__ u16 P2s[64*72];
  int bid = blockIdx.x; int z = bid & 7, itile = bid >> 3;   // z-affine for XCD L2
  int t = threadIdx.x, lane = t&63, w = t>>6, l15 = lane&15, lhi = lane>>4;
  int rbase = z*LL + itile*64;
  for(int p=0;p<16;p++){
    int rl = w*16 + p, rg = rbase + rl;
    float v = qzstate[(size_t)rg*64 + lane];
    float mx = wred_max(v);
    float e = __expf(v - mx);
    float s = wred_sum(e);
    float mk = (mask[rg] != 0) ? 1.f : 0.f;
    u16 q = f2b(e/s*mk);
    qzb[(size_t)rg*64 + lane] = q;
    qlds[rl*72 + lane] = q;
  }
  __syncthreads();
  f32x4 f[4];
  {
    const u16* Ar = &qlds[(w*16 + l15)*72 + lhi*8];
    bf16x8 a0 = ldb8(Ar), a1 = ldb8(Ar+32);
    #pragma unroll
    for(int ct=0;ct<4;ct++){
      const u16* Br = Gt2 + (size_t)(ct*16 + l15)*64 + lhi*8;
      f32x4 acc = {0.f,0.f,0.f,0.f};
      acc = MFMA(a0, ldb8(Br), acc);
      acc = MFMA(a1, ldb8(Br+32), acc);
      f[ct] = acc;
    }
  }
  #pragma unroll
  for(int jj=0;jj<4;jj++){
    float ps = 0.f;
    #pragma unroll
    for(int ct=0;ct<4;ct++){ float e = __expf(f[ct][jj]); f[ct][jj] = e; ps += e; }
    float s = g16_sum(ps);
    float iv = 1.f/s;
    #pragma unroll
    for(int ct=0;ct<4;ct++)
      P2s[(w*16 + lhi*4 + jj)*72 + ct*16 + l15] = f2b(f[ct][jj]*iv);
  }
  __syncthreads();
  {
    const u16* Ar = &P2s[(w*16 + l15)*72 + lhi*8];
    bf16x8 a0 = ldb8(Ar), a1 = ldb8(Ar+32);
    #pragma unroll
    for(int nt=0;nt<4;nt++){
      const u16* Br = Gt + (size_t)(nt*16 + l15)*64 + lhi*8;
      f32x4 acc = {0.f,0.f,0.f,0.f};
      acc = MFMA(a0, ldb8(Br), acc);
      acc = MFMA(a1, ldb8(Br+32), acc);
      #pragma unroll
      for(int jj=0;jj<4;jj++)
        MgF[((size_t)rbase + w*16 + lhi*4 + jj)*64 + nt*16 + l15] = acc[jj];
    }
  }
}

// ---- k2: per (z,c): t1[i][b], t1t[b][i], t2t[a][j]  (all K=64 GEMMs) ----
__global__ __launch_bounds__(256) void k2(const u16* __restrict__ qzb,
      const u16* __restrict__ T4t, const u16* __restrict__ Tt2,
      u16* __restrict__ t1b, u16* __restrict__ t1t, u16* __restrict__ t2t){
  int bid = blockIdx.x; int z = bid&7, c = (bid>>3)&7, itile = bid>>6;
  int zc = z*8 + c;
  int t = threadIdx.x, lane = t&63, w = t>>6, l15 = lane&15, lhi = lane>>4;
  int i0 = itile*64;
  const u16* qA = qzb + ((size_t)z*LL + i0 + w*16 + l15)*64 + lhi*8;
  bf16x8 qa0 = ldb8(qA), qa1 = ldb8(qA+32);
  const u16* tA = T4t + c*4096 + (w*16 + l15)*64 + lhi*8;
  bf16x8 ta0 = ldb8(tA), ta1 = ldb8(tA+32);
  const u16* uA = Tt2 + c*4096 + (w*16 + l15)*64 + lhi*8;
  bf16x8 ua0 = ldb8(uA), ua1 = ldb8(uA+32);
  #pragma unroll
  for(int nt=0;nt<4;nt++){
    {
      const u16* Br = T4t + c*4096 + (nt*16 + l15)*64 + lhi*8;
      f32x4 acc = {0.f,0.f,0.f,0.f};
      acc = MFMA(qa0, ldb8(Br), acc);
      acc = MFMA(qa1, ldb8(Br+32), acc);
      #pragma unroll
      for(int jj=0;jj<4;jj++)
        t1b[((size_t)zc*LL + i0 + w*16 + lhi*4 + jj)*64 + nt*16 + l15] = f2b(acc[jj]);
    }
    const u16* Br = qzb + ((size_t)z*LL + i0 + nt*16 + l15)*64 + lhi*8;
    bf16x8 qb0 = ldb8(Br), qb1 = ldb8(Br+32);
    {
      f32x4 acc = {0.f,0.f,0.f,0.f};
      acc = MFMA(ta0, qb0, acc);
      acc = MFMA(ta1, qb1, acc);
      #pragma unroll
      for(int jj=0;jj<4;jj++)
        t1t[((size_t)zc*64 + w*16 + lhi*4 + jj)*LL + i0 + nt*16 + l15] = f2b(acc[jj]);
    }
    {
      f32x4 acc = {0.f,0.f,0.f,0.f};
      acc = MFMA(ua0, qb0, acc);
      acc = MFMA(ua1, qb1, acc);
      #pragma unroll
      for(int jj=0;jj<4;jj++)
        t2t[((size_t)zc*64 + w*16 + lhi*4 + jj)*LL + i0 + nt*16 + l15] = f2b(acc[jj]);
    }
  }
}

// ---- kF: fused S -> P -> mi (iv post-scale, reg B) + mj (wave-local PpT) ----
// 3 barriers/panel; mi B-slices live in VGPRs (loaded once from L2-resident t2t).
__global__ __launch_bounds__(1024, 4) void kF(const u16* __restrict__ t1b, const u16* __restrict__ qzb,
        const u16* __restrict__ t1t, const u16* __restrict__ t2t, const float* __restrict__ mf,
        u16* __restrict__ miP, u16* __restrict__ mjP){
  extern __shared__ char smem[];
  u16*   Pp   = (u16*)smem;                    // [32][520]   33280 B (unnormalized exp)
  u16*   PpT  = (u16*)(smem + 33280);          // [16w][32][40] 40960 B (normalized, wave-local)
  float* red  = (float*)(smem + 74240);        // [32][16]     2048 B
  float* redS = (float*)(smem + 76288);        // [32]          128 B
  float* stgf = (float*)(smem + 76416);        // [2][32][68] f32  17408 B
  u16*   stg  = (u16*)smem;                    // [128][72] u16 (dump phase, reuses Pp)
  int bid = blockIdx.x;
  int z = bid&7, c = (bid>>3)&7, it = bid>>6;   // it < 4
  int zc = z*8 + c;
  int t = threadIdx.x, lane = t&63, w = t>>6, l15 = lane&15, lhi = lane>>4;
  int jc0 = w*32;                               // wave's j-slice
  int h = w>>3, wr = (w>>2)&1, wc = w&3;        // mi role
  // ---- prologue: mi B-slice (t2t rows wc*16..+16, K-half h) -> 32 VGPR ----
  bf16x8 miB[8];
  {
    const u16* Bp = t2t + ((size_t)zc*64 + wc*16 + l15)*LL + h*256 + lhi*8;
    #pragma unroll
    for(int ks=0;ks<8;ks++) miB[ks] = ldb8(Bp + ks*32);
  }
  float mfj[2];
  mfj[0] = mf[z*LL + jc0 + l15];
  mfj[1] = mf[z*LL + jc0 + 16 + l15];
  f32x4 mj[2][4];
  #pragma unroll
  for(int jt=0;jt<2;jt++)
    #pragma unroll
    for(int bt=0;bt<4;bt++) mj[jt][bt] = (f32x4){0.f,0.f,0.f,0.f};
  u16* PpTw = PpT + w*32*40;                    // wave-local transpose buffer

  for(int ip=0; ip<4; ++ip){
    int i0g = it*128 + ip*32;
    // ---- S panel (32 rows x wave's 32 cols) ----
    f32x4 S[2][2];
    #pragma unroll
    for(int rt=0;rt<2;rt++){ S[rt][0] = (f32x4){0,0,0,0}; S[rt][1] = (f32x4){0,0,0,0}; }
    #pragma unroll
    for(int rt=0;rt<2;rt++){
      const u16* Ar = t1b + ((size_t)zc*LL + i0g + rt*16 + l15)*64 + lhi*8;
      bf16x8 a0 = ldb8(Ar), a1 = ldb8(Ar+32);
      #pragma unroll
      for(int ct=0;ct<2;ct++){
        const u16* Br = qzb + ((size_t)z*LL + jc0 + ct*16 + l15)*64 + lhi*8;
        S[rt][ct] = MFMA(a0, ldb8(Br), S[rt][ct]);
        S[rt][ct] = MFMA(a1, ldb8(Br+32), S[rt][ct]);
      }
    }
    // ---- mask/diag/exp (fixed max), partial row-sums, unnormalized Pp ----
    #pragma unroll
    for(int rt=0;rt<2;rt++)
      #pragma unroll
      for(int jj=0;jj<4;jj++){
        int rloc = rt*16 + lhi*4 + jj;
        int irow = i0g + rloc;
        float mfi = mf[z*LL + irow];
        float ps = 0.f;
        #pragma unroll
        for(int ct=0;ct<2;ct++){
          int jcol = jc0 + ct*16 + l15;
          float v = S[rt][ct][jj] - ((irow==jcol)?BIGV:0.f);
          float e = mfi * mfj[ct] * __expf(v);
          S[rt][ct][jj] = e; ps += e;
          Pp[rloc*520 + jcol] = f2b(e);        // unnormalized
        }
        ps = g16_sum(ps);
        if(l15 == 0) red[rloc*16 + w] = ps;
      }
    __syncthreads();
    // ---- cooperative row-sum: red[32][16] -> redS[32] ----
    if(t < 512){
      float v = red[t];
      v += __shfl_xor(v,1,64); v += __shfl_xor(v,2,64);
      v += __shfl_xor(v,4,64); v += __shfl_xor(v,8,64);
      if((t&15)==0) redS[t>>4] = v;
    }
    __syncthreads();
    // ---- normalized wave-local PpT (no barrier needed before mj) ----
    float ivv[2][4];
    #pragma unroll
    for(int rt=0;rt<2;rt++)
      #pragma unroll
      for(int jj=0;jj<4;jj++){
        float s = redS[rt*16 + lhi*4 + jj];
        ivv[rt][jj] = s > 0.f ? 1.f/s : 0.f;
      }
    #pragma unroll
    for(int rt=0;rt<2;rt++)
      #pragma unroll
      for(int ct=0;ct<2;ct++){
        s16x4 v4 = { (short)f2b(S[rt][ct][0]*ivv[rt][0]), (short)f2b(S[rt][ct][1]*ivv[rt][1]),
                     (short)f2b(S[rt][ct][2]*ivv[rt][2]), (short)f2b(S[rt][ct][3]*ivv[rt][3]) };
        *(s16x4*)&PpTw[(ct*16 + l15)*40 + rt*16 + lhi*4] = v4;
      }
    // ---- mi: A = Pp (unnorm, LDS), B = miB (regs); iv post-scale on D rows ----
    {
      f32x4 mia = {0.f,0.f,0.f,0.f};
      const u16* Ab = Pp + (wr*16 + l15)*520 + h*256 + lhi*8;
      #pragma unroll
      for(int ks=0;ks<8;ks++)
        mia = MFMA(ldb8(Ab + ks*32), miB[ks], mia);
      #pragma unroll
      for(int jj=0;jj<4;jj++)
        stgf[(h*32 + wr*16 + lhi*4 + jj)*68 + wc*16 + l15] = mia[jj]*ivv[wr][jj];
    }
    // ---- mj accumulate: A = own PpT (K=32), B = t1t (global, L2-hot) ----
    {
      bf16x8 av[2];
      #pragma unroll
      for(int jt=0;jt<2;jt++)
        av[jt] = ldb8(PpTw + (jt*16 + l15)*40 + lhi*8);
      #pragma unroll
      for(int bt=0;bt<4;bt++){
        bf16x8 b = ldb8(t1t + ((size_t)zc*64 + bt*16 + l15)*LL + i0g + lhi*8);
        #pragma unroll
        for(int jt=0;jt<2;jt++) mj[jt][bt] = MFMA(av[jt], b, mj[jt][bt]);
      }
    }
    __syncthreads();
    // ---- mi store: sum 2 K-halves, 16B coalesced ----
    if(t < 512){
      int r = t>>4, cc = t&15;
      f32x4 v0 = *(const f32x4*)&stgf[r*68 + cc*4];
      f32x4 v1 = *(const f32x4*)&stgf[(32+r)*68 + cc*4];
      s16x4 o = { (short)f2b(v0[0]+v1[0]), (short)f2b(v0[1]+v1[1]),
                  (short)f2b(v0[2]+v1[2]), (short)f2b(v0[3]+v1[3]) };
      *(s16x4*)&miP[((size_t)z*LL + i0g + r)*512 + c*64 + cc*4] = o;
    }
    __syncthreads();
  }
  // ---- mj dump: 4 rounds of 128 j-rows via LDS (reuses Pp region) ----
  for(int r=0;r<4;r++){
    if((w>>2) == r){
      int jl = (w&3)*32;
      #pragma unroll
      for(int jt=0;jt<2;jt++)
        #pragma unroll
        for(int bt=0;bt<4;bt++)
          #pragma unroll
          for(int jj=0;jj<4;jj++)
            stg[(jl + jt*16 + lhi*4 + jj)*72 + bt*16 + l15] = f2b(mj[jt][bt][jj]);
    }
    __syncthreads();
    {
      int jr = t>>3, ch = t&7;
      *(bf16x8*)&mjP[(((size_t)(it*8 + z))*LL + r*128 + jr)*512 + c*64 + ch*8]
        = *(const bf16x8*)&stg[jr*72 + ch*8];
    }
    __syncthreads();
  }
}

// ---- k5c: out = (unary + Mg + sum_c miP + sum_{it,c} mjP) * m1 ----
__global__ __launch_bounds__(256) void k5c(const u16* __restrict__ miP, const u16* __restrict__ mjP,
      const float* __restrict__ MgF, const float* __restrict__ unary, const float* __restrict__ mf,
      float* __restrict__ outq){
  int bid = blockIdx.x; int z = bid&7, itile = bid>>3;   // itile < 16
  int t = threadIdx.x;
  int r = t>>3, c8 = t&7;
  int row = itile*32 + r;
  size_t gr = (size_t)z*LL + row;
  const float* mgp = &MgF[gr*64 + c8*8];
  f32x4 aclo = *(const f32x4*)mgp;
  f32x4 achi = *(const f32x4*)(mgp + 4);
  #pragma unroll
  for(int c=0;c<8;c++){
    bf16x8 v = ldb8(&miP[gr*512 + c*64 + c8*8]);
    aclo[0]+=b2f((u16)v[0]); aclo[1]+=b2f((u16)v[1]); aclo[2]+=b2f((u16)v[2]); aclo[3]+=b2f((u16)v[3]);
    achi[0]+=b2f((u16)v[4]); achi[1]+=b2f((u16)v[5]); achi[2]+=b2f((u16)v[6]); achi[3]+=b2f((u16)v[7]);
  }
  #pragma unroll
  for(int s=0;s<4;s++)
    #pragma unroll
    for(int c=0;c<8;c++){
      bf16x8 v = ldb8(&mjP[(((size_t)(s*8 + z))*LL + row)*512 + c*64 + c8*8]);
      aclo[0]+=b2f((u16)v[0]); aclo[1]+=b2f((u16)v[1]); aclo[2]+=b2f((u16)v[2]); aclo[3]+=b2f((u16)v[3]);
      achi[0]+=b2f((u16)v[4]); achi[1]+=b2f((u16)v[5]); achi[2]+=b2f((u16)v[6]); achi[3]+=b2f((u16)v[7]);
    }
  f32x4 u0 = *(const f32x4*)&unary[gr*64 + c8*8];
  f32x4 u1 = *(const f32x4*)&unary[gr*64 + c8*8 + 4];
  float mk = mf[gr];
  f32x4 o0, o1;
  #pragma unroll
  for(int k=0;k<4;k++){ o0[k] = (u0[k] + aclo[k]) * mk; o1[k] = (u1[k] + achi[k]) * mk; }
  *(f32x4*)&outq[gr*64 + c8*8]     = o0;
  *(f32x4*)&outq[gr*64 + c8*8 + 4] = o1;
}

extern "C" void kernel_launch(void* const* d_in, const int* in_sizes, int n_in,
                              void* d_out, int out_size, void* d_ws, size_t ws_size,
                              hipStream_t stream) {
  const float* x       = (const float*)d_in[0];
  const int*   mask    = (const int*)d_in[1];
  const float* ternary = (const float*)d_in[2];
  const float* gw      = (const float*)d_in[3];
  float* out = (float*)d_out;

  const size_t NE = (size_t)BB*LL*64;          // 262144
  char* p = (char*)d_ws;
  auto alloc = [&](size_t bytes)->void*{
    void* r = (void*)p; p += (bytes + 255) & ~(size_t)255; return r;
  };
  float* unary   = (float*)alloc(NE*4);
  float* qzstate = (float*)alloc(NE*4);
  float* mf      = (float*)alloc((size_t)BB*LL*4);
  u16*   qzb     = (u16*)alloc(NE*2);
  u16*   t1b     = (u16*)alloc((size_t)BB*HH*LL*64*2);   // 4.2 MB
  u16*   t1t     = (u16*)alloc((size_t)BB*HH*LL*64*2);   // 4.2 MB
  u16*   t2t     = (u16*)alloc((size_t)BB*HH*LL*64*2);   // 4.2 MB
  float* MgF     = (float*)alloc(NE*4);                  // 1 MB
  u16*   miP     = (u16*)alloc((size_t)BB*LL*512*2);     // 4.2 MB
  u16*   mjP     = (u16*)alloc((size_t)32*LL*512*2);     // 16.8 MB
  u16*   T4t     = (u16*)alloc(32768*2);
  u16*   Tt2     = (u16*)alloc(32768*2);
  u16*   Gt      = (u16*)alloc(4096*2);
  u16*   Gt2     = (u16*)alloc(4096*2);

  const int KF_LDS = 93824;  // Pp 33280 + PpT 40960 + red 2048 + redS 128 + stgf 17408
  hipFuncSetAttribute(reinterpret_cast<const void*>(kF),
                      hipFuncAttributeMaxDynamicSharedMemorySize, KF_LDS);

  kp_prep<<<128, 256, 0, stream>>>(ternary, gw, T4t, Tt2, Gt, Gt2);
  k0_init<<<(int)(NE/256), 256, 0, stream>>>(x, mask, unary, qzstate, mf);
  for(int it=0; it<4; ++it){
    kA<<<BB*8, 256, 0, stream>>>(qzstate, mask, Gt2, Gt, qzb, MgF);
    k2<<<512, 256, 0, stream>>>(qzb, T4t, Tt2, t1b, t1t, t2t);
    kF<<<256, 1024, KF_LDS, stream>>>(t1b, qzb, t1t, t2t, mf, miP, mjP);
    float* outq = (it==3) ? out : qzstate;
    k5c<<<128, 256, 0, stream>>>(miP, mjP, MgF, unary, mf, outq);
  }
}

// Round 9
// 296.031 us; speedup vs baseline: 1.3553x; 1.3553x over previous
//
#include <hip/hip_runtime.h>

#define BB 8
#define LL 512
#define HH 8
#define BIGV (1e9f)

typedef unsigned short u16;
typedef __attribute__((ext_vector_type(8))) short bf16x8;
typedef __attribute__((ext_vector_type(4))) short s16x4;
typedef __attribute__((ext_vector_type(4))) float f32x4;

#define MFMA(a,b,c) __builtin_amdgcn_mfma_f32_16x16x32_bf16(a,b,c,0,0,0)

__device__ __forceinline__ u16 f2b(float f){
  unsigned u = __float_as_uint(f);
  u = (u + 0x7fffu + ((u>>16)&1u)) >> 16;
  return (u16)u;
}
__device__ __forceinline__ float b2f(u16 s){ return __uint_as_float(((unsigned)s)<<16); }
__device__ __forceinline__ bf16x8 ldb8(const u16* p){ return *(const bf16x8*)p; }

__device__ __forceinline__ float wred_max(float v){
  #pragma unroll
  for(int off=32;off>0;off>>=1) v = fmaxf(v, __shfl_xor(v, off, 64));
  return v;
}
__device__ __forceinline__ float wred_sum(float v){
  #pragma unroll
  for(int off=32;off>0;off>>=1) v += __shfl_xor(v, off, 64);
  return v;
}
__device__ __forceinline__ float g16_sum(float v){
  v += __shfl_xor(v,1,64); v += __shfl_xor(v,2,64);
  v += __shfl_xor(v,4,64); v += __shfl_xor(v,8,64);
  return v;
}

// ---- tables: T4t[c][b][a], Tt2[c][a][b], Gt[a][j], Gt2[j][a] ----
__global__ void kp_prep(const float* __restrict__ T, const float* __restrict__ gw,
                        u16* __restrict__ T4t, u16* __restrict__ Tt2,
                        u16* __restrict__ Gt, u16* __restrict__ Gt2){
  int idx = blockIdx.x*256 + threadIdx.x;   // < 32768
  { int c=idx>>12, b=(idx>>6)&63, a=idx&63; T4t[idx] = f2b(T[(a*64+b)*8+c]); }
  { int c=idx>>12, a=(idx>>6)&63, b=idx&63; Tt2[idx] = f2b(T[(a*64+b)*8+c]); }
  if(idx < 4096){
    int a=idx>>6, j=idx&63;
    Gt[idx]  = f2b(gw[j*64+a]);   // Gt[a][j]
    Gt2[idx] = f2b(gw[idx]);      // Gt2[j][a]
  }
}

// ---- k0: unary = (x+pe)*m1 ; qzstate = unary ; mf = mask as float ----
__global__ void k0_init(const float* __restrict__ x, const int* __restrict__ mask,
                        float* __restrict__ unary, float* __restrict__ qzstate,
                        float* __restrict__ mf){
  int idx = blockIdx.x*256 + threadIdx.x;
  int d = idx & 63; int row = idx >> 6;
  int pos = row & (LL-1);
  int k2 = d & ~1;
  float div = __expf(-(float)k2 * 0.14391156962f);  // ln(10000)/64
  float arg = (float)pos * div;
  float pe = (d & 1) ? cosf(arg) : sinf(arg);
  float mk = (mask[row] != 0) ? 1.f : 0.f;
  float u = (x[idx] + pe) * mk;
  unary[idx] = u; qzstate[idx] = u;
  if(d == 0) mf[row] = mk;
}

// ---- kA: softmax64 -> qzb ; P2 softmax + Mg = P2@gw -> MgF ----
__global__ __launch_bounds__(256) void kA(const float* __restrict__ qzstate,
      const int* __restrict__ mask, const u16* __restrict__ Gt2, const u16* __restrict__ Gt,
      u16* __restrict__ qzb, float* __restrict__ MgF){
  __shared__ u16 qlds[64*72];
  __shared__ u16 P2s[64*72];
  int bid = blockIdx.x; int z = bid & 7, itile = bid >> 3;   // z-affine for XCD L2
  int t = threadIdx.x, lane = t&63, w = t>>6, l15 = lane&15, lhi = lane>>4;
  int rbase = z*LL + itile*64;
  for(int p=0;p<16;p++){
    int rl = w*16 + p, rg = rbase + rl;
    float v = qzstate[(size_t)rg*64 + lane];
    float mx = wred_max(v);
    float e = __expf(v - mx);
    float s = wred_sum(e);
    float mk = (mask[rg] != 0) ? 1.f : 0.f;
    u16 q = f2b(e/s*mk);
    qzb[(size_t)rg*64 + lane] = q;
    qlds[rl*72 + lane] = q;
  }
  __syncthreads();
  f32x4 f[4];
  {
    const u16* Ar = &qlds[(w*16 + l15)*72 + lhi*8];
    bf16x8 a0 = ldb8(Ar), a1 = ldb8(Ar+32);
    #pragma unroll
    for(int ct=0;ct<4;ct++){
      const u16* Br = Gt2 + (size_t)(ct*16 + l15)*64 + lhi*8;
      f32x4 acc = {0.f,0.f,0.f,0.f};
      acc = MFMA(a0, ldb8(Br), acc);
      acc = MFMA(a1, ldb8(Br+32), acc);
      f[ct] = acc;
    }
  }
  #pragma unroll
  for(int jj=0;jj<4;jj++){
    float ps = 0.f;
    #pragma unroll
    for(int ct=0;ct<4;ct++){ float e = __expf(f[ct][jj]); f[ct][jj] = e; ps += e; }
    float s = g16_sum(ps);
    float iv = 1.f/s;
    #pragma unroll
    for(int ct=0;ct<4;ct++)
      P2s[(w*16 + lhi*4 + jj)*72 + ct*16 + l15] = f2b(f[ct][jj]*iv);
  }
  __syncthreads();
  {
    const u16* Ar = &P2s[(w*16 + l15)*72 + lhi*8];
    bf16x8 a0 = ldb8(Ar), a1 = ldb8(Ar+32);
    #pragma unroll
    for(int nt=0;nt<4;nt++){
      const u16* Br = Gt + (size_t)(nt*16 + l15)*64 + lhi*8;
      f32x4 acc = {0.f,0.f,0.f,0.f};
      acc = MFMA(a0, ldb8(Br), acc);
      acc = MFMA(a1, ldb8(Br+32), acc);
      #pragma unroll
      for(int jj=0;jj<4;jj++)
        MgF[((size_t)rbase + w*16 + lhi*4 + jj)*64 + nt*16 + l15] = acc[jj];
    }
  }
}

// ---- k2: per (z,c): t1[i][b], t1t[b][i], t2t[a][j]  (all K=64 GEMMs) ----
__global__ __launch_bounds__(256) void k2(const u16* __restrict__ qzb,
      const u16* __restrict__ T4t, const u16* __restrict__ Tt2,
      u16* __restrict__ t1b, u16* __restrict__ t1t, u16* __restrict__ t2t){
  int bid = blockIdx.x; int z = bid&7, c = (bid>>3)&7, itile = bid>>6;
  int zc = z*8 + c;
  int t = threadIdx.x, lane = t&63, w = t>>6, l15 = lane&15, lhi = lane>>4;
  int i0 = itile*64;
  const u16* qA = qzb + ((size_t)z*LL + i0 + w*16 + l15)*64 + lhi*8;
  bf16x8 qa0 = ldb8(qA), qa1 = ldb8(qA+32);
  const u16* tA = T4t + c*4096 + (w*16 + l15)*64 + lhi*8;
  bf16x8 ta0 = ldb8(tA), ta1 = ldb8(tA+32);
  const u16* uA = Tt2 + c*4096 + (w*16 + l15)*64 + lhi*8;
  bf16x8 ua0 = ldb8(uA), ua1 = ldb8(uA+32);
  #pragma unroll
  for(int nt=0;nt<4;nt++){
    {
      const u16* Br = T4t + c*4096 + (nt*16 + l15)*64 + lhi*8;
      f32x4 acc = {0.f,0.f,0.f,0.f};
      acc = MFMA(qa0, ldb8(Br), acc);
      acc = MFMA(qa1, ldb8(Br+32), acc);
      #pragma unroll
      for(int jj=0;jj<4;jj++)
        t1b[((size_t)zc*LL + i0 + w*16 + lhi*4 + jj)*64 + nt*16 + l15] = f2b(acc[jj]);
    }
    const u16* Br = qzb + ((size_t)z*LL + i0 + nt*16 + l15)*64 + lhi*8;
    bf16x8 qb0 = ldb8(Br), qb1 = ldb8(Br+32);
    {
      f32x4 acc = {0.f,0.f,0.f,0.f};
      acc = MFMA(ta0, qb0, acc);
      acc = MFMA(ta1, qb1, acc);
      #pragma unroll
      for(int jj=0;jj<4;jj++)
        t1t[((size_t)zc*64 + w*16 + lhi*4 + jj)*LL + i0 + nt*16 + l15] = f2b(acc[jj]);
    }
    {
      f32x4 acc = {0.f,0.f,0.f,0.f};
      acc = MFMA(ua0, qb0, acc);
      acc = MFMA(ua1, qb1, acc);
      #pragma unroll
      for(int jj=0;jj<4;jj++)
        t2t[((size_t)zc*64 + w*16 + lhi*4 + jj)*LL + i0 + nt*16 + l15] = f2b(acc[jj]);
    }
  }
}

// ---- kF: fused S -> P -> mi (LDS t2s B, iv post-scale) + mj (wave-local PpT) ----
// 3 barriers/panel; t2s LDS-staged (round-7 lesson: register tiles spill at this
// occupancy — round-8 lesson); single-pass mj dump reusing dead t2s/Pp space.
__global__ __launch_bounds__(1024) void kF(const u16* __restrict__ t1b, const u16* __restrict__ qzb,
        const u16* __restrict__ t1t, const u16* __restrict__ t2t, const float* __restrict__ mf,
        u16* __restrict__ miP, u16* __restrict__ mjP){
  extern __shared__ char smem[];
  u16*   t2s  = (u16*)smem;                    // [64][520]   66560 B
  u16*   Pp   = (u16*)(smem + 66560);          // [32][520]   33280 B (unnormalized exp)
  u16*   PpT  = (u16*)(smem + 99840);          // [16w][32][40] 40960 B (normalized, wave-local)
  float* red  = (float*)(smem + 140800);       // [32][16]     2048 B
  float* redS = (float*)(smem + 142848);       // [32]          128 B
  float* stgf = (float*)(smem + 142976);       // [2][32][68] f32 17408 B  (end 160384)
  u16*   stg  = (u16*)smem;                    // [512][72] dump (reuses t2s+Pp, 73728 B)
  int bid = blockIdx.x;
  int z = bid&7, c = (bid>>3)&7, it = bid>>6;   // it < 4
  int zc = z*8 + c;
  int t = threadIdx.x, lane = t&63, w = t>>6, l15 = lane&15, lhi = lane>>4;
  int jc0 = w*32;                               // wave's j-slice
  int h = w>>3, wr = (w>>2)&1, wc = w&3;        // mi role
  // ---- stage t2t[zc] -> t2s (4 passes x 1024 threads x 16B); visible at B1 ----
  #pragma unroll
  for(int m=0;m<4;m++){
    int e = (m*1024 + t)*8;
    int a = e >> 9, j = e & 511;
    *(bf16x8*)&t2s[a*520 + j] = ldb8(t2t + ((size_t)zc*64 + a)*LL + j);
  }
  float mfj[2];
  mfj[0] = mf[z*LL + jc0 + l15];
  mfj[1] = mf[z*LL + jc0 + 16 + l15];
  f32x4 mj[2][4];
  #pragma unroll
  for(int jt=0;jt<2;jt++)
    #pragma unroll
    for(int bt=0;bt<4;bt++) mj[jt][bt] = (f32x4){0.f,0.f,0.f,0.f};
  u16* PpTw = PpT + w*32*40;                    // wave-local transpose buffer

  for(int ip=0; ip<4; ++ip){
    int i0g = it*128 + ip*32;
    // ---- S panel (32 rows x wave's 32 cols) ----
    f32x4 S[2][2];
    #pragma unroll
    for(int rt=0;rt<2;rt++){ S[rt][0] = (f32x4){0,0,0,0}; S[rt][1] = (f32x4){0,0,0,0}; }
    #pragma unroll
    for(int rt=0;rt<2;rt++){
      const u16* Ar = t1b + ((size_t)zc*LL + i0g + rt*16 + l15)*64 + lhi*8;
      bf16x8 a0 = ldb8(Ar), a1 = ldb8(Ar+32);
      #pragma unroll
      for(int ct=0;ct<2;ct++){
        const u16* Br = qzb + ((size_t)z*LL + jc0 + ct*16 + l15)*64 + lhi*8;
        S[rt][ct] = MFMA(a0, ldb8(Br), S[rt][ct]);
        S[rt][ct] = MFMA(a1, ldb8(Br+32), S[rt][ct]);
      }
    }
    // ---- mask/diag/exp (fixed max), partial row-sums, unnormalized Pp ----
    #pragma unroll
    for(int rt=0;rt<2;rt++)
      #pragma unroll
      for(int jj=0;jj<4;jj++){
        int rloc = rt*16 + lhi*4 + jj;
        int irow = i0g + rloc;
        float mfi = mf[z*LL + irow];
        float ps = 0.f;
        #pragma unroll
        for(int ct=0;ct<2;ct++){
          int jcol = jc0 + ct*16 + l15;
          float v = S[rt][ct][jj] - ((irow==jcol)?BIGV:0.f);
          float e = mfi * mfj[ct] * __expf(v);
          S[rt][ct][jj] = e; ps += e;
          Pp[rloc*520 + jcol] = f2b(e);        // unnormalized
        }
        ps = g16_sum(ps);
        if(l15 == 0) red[rloc*16 + w] = ps;
      }
    __syncthreads();                            // B1: Pp/red (and t2s, ip=0) ready
    // ---- cooperative row-sum: red[32][16] -> redS[32] ----
    if(t < 512){
      float v = red[t];
      v += __shfl_xor(v,1,64); v += __shfl_xor(v,2,64);
      v += __shfl_xor(v,4,64); v += __shfl_xor(v,8,64);
      if((t&15)==0) redS[t>>4] = v;
    }
    __syncthreads();                            // B1.5: redS ready
    float ivv[2][4];
    #pragma unroll
    for(int rt=0;rt<2;rt++)
      #pragma unroll
      for(int jj=0;jj<4;jj++){
        float s = redS[rt*16 + lhi*4 + jj];
        ivv[rt][jj] = s > 0.f ? 1.f/s : 0.f;
      }
    // ---- normalized wave-local PpT (no barrier needed before mj) ----
    #pragma unroll
    for(int rt=0;rt<2;rt++)
      #pragma unroll
      for(int ct=0;ct<2;ct++){
        s16x4 v4 = { (short)f2b(S[rt][ct][0]*ivv[rt][0]), (short)f2b(S[rt][ct][1]*ivv[rt][1]),
                     (short)f2b(S[rt][ct][2]*ivv[rt][2]), (short)f2b(S[rt][ct][3]*ivv[rt][3]) };
        *(s16x4*)&PpTw[(ct*16 + l15)*40 + rt*16 + lhi*4] = v4;
      }
    // ---- mi: A = Pp (unnorm, LDS), B = t2s (LDS); iv post-scale ----
    {
      f32x4 mia = {0.f,0.f,0.f,0.f};
      const u16* Ab = Pp + (wr*16 + l15)*520 + h*256 + lhi*8;
      const u16* Bb = t2s + (wc*16 + l15)*520 + h*256 + lhi*8;
      #pragma unroll
      for(int ks=0;ks<8;ks++)
        mia = MFMA(ldb8(Ab + ks*32), ldb8(Bb + ks*32), mia);
      #pragma unroll
      for(int jj=0;jj<4;jj++)
        stgf[(h*32 + wr*16 + lhi*4 + jj)*68 + wc*16 + l15] = mia[jj]*ivv[wr][jj];
    }
    // ---- mj accumulate: A = own PpT (K=32), B = t1t (global, L2-hot) ----
    {
      bf16x8 av[2];
      #pragma unroll
      for(int jt=0;jt<2;jt++)
        av[jt] = ldb8(PpTw + (jt*16 + l15)*40 + lhi*8);
      #pragma unroll
      for(int bt=0;bt<4;bt++){
        bf16x8 b = ldb8(t1t + ((size_t)zc*64 + bt*16 + l15)*LL + i0g + lhi*8);
        #pragma unroll
        for(int jt=0;jt<2;jt++) mj[jt][bt] = MFMA(av[jt], b, mj[jt][bt]);
      }
    }
    __syncthreads();                            // B2: stgf ready; Pp/red/t2s reads done
    // ---- mi store: sum 2 K-halves, 16B coalesced (overlaps next panel's exp) ----
    if(t < 512){
      int r = t>>4, cc = t&15;
      f32x4 v0 = *(const f32x4*)&stgf[r*68 + cc*4];
      f32x4 v1 = *(const f32x4*)&stgf[(32+r)*68 + cc*4];
      s16x4 o = { (short)f2b(v0[0]+v1[0]), (short)f2b(v0[1]+v1[1]),
                  (short)f2b(v0[2]+v1[2]), (short)f2b(v0[3]+v1[3]) };
      *(s16x4*)&miP[((size_t)z*LL + i0g + r)*512 + c*64 + cc*4] = o;
    }
    // no trailing barrier: next exp writes Pp/red (consumed pre-B2); next stgf
    // write happens after next B1.5, by which B1 has fenced this mi store.
  }
  // ---- mj dump: single pass, stg[512][72] reuses dead t2s+Pp space ----
  #pragma unroll
  for(int jt=0;jt<2;jt++)
    #pragma unroll
    for(int bt=0;bt<4;bt++)
      #pragma unroll
      for(int jj=0;jj<4;jj++)
        stg[(jc0 + jt*16 + lhi*4 + jj)*72 + bt*16 + l15] = f2b(mj[jt][bt][jj]);
  __syncthreads();
  #pragma unroll
  for(int q=0;q<4;q++){
    int e = q*1024 + t;
    int j = e >> 3, ch = e & 7;
    *(bf16x8*)&mjP[(((size_t)(it*8 + z))*LL + j)*512 + c*64 + ch*8]
      = *(const bf16x8*)&stg[j*72 + ch*8];
  }
}

// ---- k5c: out = (unary + Mg + sum_c miP + sum_{it,c} mjP) * m1 ----
__global__ __launch_bounds__(256) void k5c(const u16* __restrict__ miP, const u16* __restrict__ mjP,
      const float* __restrict__ MgF, const float* __restrict__ unary, const float* __restrict__ mf,
      float* __restrict__ outq){
  int bid = blockIdx.x; int z = bid&7, itile = bid>>3;   // itile < 16
  int t = threadIdx.x;
  int r = t>>3, c8 = t&7;
  int row = itile*32 + r;
  size_t gr = (size_t)z*LL + row;
  const float* mgp = &MgF[gr*64 + c8*8];
  f32x4 aclo = *(const f32x4*)mgp;
  f32x4 achi = *(const f32x4*)(mgp + 4);
  #pragma unroll
  for(int c=0;c<8;c++){
    bf16x8 v = ldb8(&miP[gr*512 + c*64 + c8*8]);
    aclo[0]+=b2f((u16)v[0]); aclo[1]+=b2f((u16)v[1]); aclo[2]+=b2f((u16)v[2]); aclo[3]+=b2f((u16)v[3]);
    achi[0]+=b2f((u16)v[4]); achi[1]+=b2f((u16)v[5]); achi[2]+=b2f((u16)v[6]); achi[3]+=b2f((u16)v[7]);
  }
  #pragma unroll
  for(int s=0;s<4;s++)
    #pragma unroll
    for(int c=0;c<8;c++){
      bf16x8 v = ldb8(&mjP[(((size_t)(s*8 + z))*LL + row)*512 + c*64 + c8*8]);
      aclo[0]+=b2f((u16)v[0]); aclo[1]+=b2f((u16)v[1]); aclo[2]+=b2f((u16)v[2]); aclo[3]+=b2f((u16)v[3]);
      achi[0]+=b2f((u16)v[4]); achi[1]+=b2f((u16)v[5]); achi[2]+=b2f((u16)v[6]); achi[3]+=b2f((u16)v[7]);
    }
  f32x4 u0 = *(const f32x4*)&unary[gr*64 + c8*8];
  f32x4 u1 = *(const f32x4*)&unary[gr*64 + c8*8 + 4];
  float mk = mf[gr];
  f32x4 o0, o1;
  #pragma unroll
  for(int k=0;k<4;k++){ o0[k] = (u0[k] + aclo[k]) * mk; o1[k] = (u1[k] + achi[k]) * mk; }
  *(f32x4*)&outq[gr*64 + c8*8]     = o0;
  *(f32x4*)&outq[gr*64 + c8*8 + 4] = o1;
}

extern "C" void kernel_launch(void* const* d_in, const int* in_sizes, int n_in,
                              void* d_out, int out_size, void* d_ws, size_t ws_size,
                              hipStream_t stream) {
  const float* x       = (const float*)d_in[0];
  const int*   mask    = (const int*)d_in[1];
  const float* ternary = (const float*)d_in[2];
  const float* gw      = (const float*)d_in[3];
  float* out = (float*)d_out;

  const size_t NE = (size_t)BB*LL*64;          // 262144
  char* p = (char*)d_ws;
  auto alloc = [&](size_t bytes)->void*{
    void* r = (void*)p; p += (bytes + 255) & ~(size_t)255; return r;
  };
  float* unary   = (float*)alloc(NE*4);
  float* qzstate = (float*)alloc(NE*4);
  float* mf      = (float*)alloc((size_t)BB*LL*4);
  u16*   qzb     = (u16*)alloc(NE*2);
  u16*   t1b     = (u16*)alloc((size_t)BB*HH*LL*64*2);   // 4.2 MB
  u16*   t1t     = (u16*)alloc((size_t)BB*HH*LL*64*2);   // 4.2 MB
  u16*   t2t     = (u16*)alloc((size_t)BB*HH*LL*64*2);   // 4.2 MB
  float* MgF     = (float*)alloc(NE*4);                  // 1 MB
  u16*   miP     = (u16*)alloc((size_t)BB*LL*512*2);     // 4.2 MB
  u16*   mjP     = (u16*)alloc((size_t)32*LL*512*2);     // 16.8 MB
  u16*   T4t     = (u16*)alloc(32768*2);
  u16*   Tt2     = (u16*)alloc(32768*2);
  u16*   Gt      = (u16*)alloc(4096*2);
  u16*   Gt2     = (u16*)alloc(4096*2);

  const int KF_LDS = 160384;  // t2s 66560 + Pp 33280 + PpT 40960 + red 2048 + redS 128 + stgf 17408
  hipFuncSetAttribute(reinterpret_cast<const void*>(kF),
                      hipFuncAttributeMaxDynamicSharedMemorySize, KF_LDS);

  kp_prep<<<128, 256, 0, stream>>>(ternary, gw, T4t, Tt2, Gt, Gt2);
  k0_init<<<(int)(NE/256), 256, 0, stream>>>(x, mask, unary, qzstate, mf);
  for(int it=0; it<4; ++it){
    kA<<<BB*8, 256, 0, stream>>>(qzstate, mask, Gt2, Gt, qzb, MgF);
    k2<<<512, 256, 0, stream>>>(qzb, T4t, Tt2, t1b, t1t, t2t);
    kF<<<256, 1024, KF_LDS, stream>>>(t1b, qzb, t1t, t2t, mf, miP, mjP);
    float* outq = (it==3) ? out : qzstate;
    k5c<<<128, 256, 0, stream>>>(miP, mjP, MgF, unary, mf, outq);
  }
}